// Round 9
// baseline (691.992 us; speedup 1.0000x reference)
//
#include <hip/hip_runtime.h>

#define GG 64   // num_graphs (fixed by problem)
typedef unsigned long long ull;
typedef unsigned short u16;

__device__ __forceinline__ u16 f2b(float x) {          // fp32 -> bf16 (RN-even)
    unsigned u = __float_as_uint(x);
    return (u16)((u + 0x7FFFu + ((u >> 16) & 1u)) >> 16);
}

// unpack uint4 (8 bf16) and add into acc[8]
__device__ __forceinline__ void add8(const uint4 q, float* acc) {
    acc[0] += __uint_as_float(q.x << 16);
    acc[1] += __uint_as_float(q.x & 0xFFFF0000u);
    acc[2] += __uint_as_float(q.y << 16);
    acc[3] += __uint_as_float(q.y & 0xFFFF0000u);
    acc[4] += __uint_as_float(q.z << 16);
    acc[5] += __uint_as_float(q.z & 0xFFFF0000u);
    acc[6] += __uint_as_float(q.w << 16);
    acc[7] += __uint_as_float(q.w & 0xFFFF0000u);
}

// ---------------- CSR build ----------------
__global__ void k_hist(const int* __restrict__ dst, int* __restrict__ cnt, int E) {
    int e = blockIdx.x * blockDim.x + threadIdx.x;
    if (e < E) atomicAdd(&cnt[dst[e]], 1);
}

__global__ void k_dis(const int* __restrict__ cnt, float* __restrict__ dis, int n) {
    int i = blockIdx.x * blockDim.x + threadIdx.x;
    if (i < n) dis[i] = rsqrtf((float)cnt[i] + 1.0f);
}

__global__ void k_scanA(const int* __restrict__ cnt, int* __restrict__ rp,
                        int* __restrict__ bsum, int n) {
    __shared__ int s[256];
    int i = blockIdx.x * 256 + threadIdx.x;
    int v = (i < n) ? cnt[i] : 0;
    s[threadIdx.x] = v;
    __syncthreads();
    for (int off = 1; off < 256; off <<= 1) {
        int t = (threadIdx.x >= off) ? s[threadIdx.x - off] : 0;
        __syncthreads();
        s[threadIdx.x] += t;
        __syncthreads();
    }
    if (i < n) rp[i] = s[threadIdx.x] - v;
    if (threadIdx.x == 255) bsum[blockIdx.x] = s[255];
}

__global__ void k_scanB(int* __restrict__ bsum, int nb) {
    __shared__ int s[512];
    int v = (threadIdx.x < nb) ? bsum[threadIdx.x] : 0;
    s[threadIdx.x] = v;
    __syncthreads();
    for (int off = 1; off < 512; off <<= 1) {
        int t = (threadIdx.x >= off) ? s[threadIdx.x - off] : 0;
        __syncthreads();
        s[threadIdx.x] += t;
        __syncthreads();
    }
    if (threadIdx.x < nb) bsum[threadIdx.x] = s[threadIdx.x] - v;
}

__global__ void k_scanC(int* __restrict__ rp, const int* __restrict__ bsum,
                        int* __restrict__ cursor, int n, int E) {
    int i = blockIdx.x * 256 + threadIdx.x;
    if (i < n) {
        int r = rp[i] + bsum[blockIdx.x];
        rp[i] = r;
        cursor[i] = r;
    }
    if (i == 0) rp[n] = E;
}

// scatter: 4-byte records (src only; weights folded into hw via dis pre-scaling)
__global__ void k_scatter(const int* __restrict__ src, const int* __restrict__ dst,
                          int* __restrict__ cursor, int* __restrict__ epack, int E) {
    int e = blockIdx.x * blockDim.x + threadIdx.x;
    if (e >= E) return;
    int s = src[e], d = dst[e];
    int pos = atomicAdd(&cursor[d], 1);
    epack[pos] = s;
}

// ---------------- tiled GEMM + dis-fold: hwb[n,FOUT](bf16) = (h @ W) * dis[n] ------
template <int FIN, int FOUT>
__global__ __launch_bounds__(256) void k_mm(const float* __restrict__ h,
                                            const float* __restrict__ W,
                                            const float* __restrict__ dis,
                                            u16* __restrict__ hw, int n) {
    constexpr int FX  = FOUT / 4;
    constexpr int TY  = 256 / FX;
    constexpr int NT  = TY * 4;
    constexpr int LDA = FIN + ((FOUT == 64) ? 2 : 1);
    __shared__ float sA[NT * LDA];
    __shared__ float sW[FIN * FOUT];

    for (int i = threadIdx.x; i < FIN * FOUT / 4; i += 256)
        ((float4*)sW)[i] = ((const float4*)W)[i];

    const int node0 = blockIdx.x * NT;
    constexpr int LD4 = NT * FIN / 4 / 256;
    #pragma unroll
    for (int i = 0; i < LD4; ++i) {
        int idx4 = i * 256 + threadIdx.x;
        int row = idx4 / (FIN / 4);
        int c4  = idx4 % (FIN / 4);
        int gn  = node0 + row;
        float4 v = make_float4(0.f, 0.f, 0.f, 0.f);
        if (gn < n) v = ((const float4*)(h + (long long)gn * FIN))[c4];
        float* p = &sA[row * LDA + c4 * 4];
        p[0] = v.x; p[1] = v.y; p[2] = v.z; p[3] = v.w;
    }
    __syncthreads();

    const int tx = threadIdx.x % FX;
    const int ty = threadIdx.x / FX;
    float acc[4][4];
    #pragma unroll
    for (int i = 0; i < 4; ++i)
        #pragma unroll
        for (int j = 0; j < 4; ++j) acc[i][j] = 0.f;

    #pragma unroll 8
    for (int k = 0; k < FIN; ++k) {
        float4 wv = *((const float4*)&sW[k * FOUT + tx * 4]);
        float a0 = sA[(ty * 4 + 0) * LDA + k];
        float a1 = sA[(ty * 4 + 1) * LDA + k];
        float a2 = sA[(ty * 4 + 2) * LDA + k];
        float a3 = sA[(ty * 4 + 3) * LDA + k];
        acc[0][0] = fmaf(a0, wv.x, acc[0][0]); acc[0][1] = fmaf(a0, wv.y, acc[0][1]);
        acc[0][2] = fmaf(a0, wv.z, acc[0][2]); acc[0][3] = fmaf(a0, wv.w, acc[0][3]);
        acc[1][0] = fmaf(a1, wv.x, acc[1][0]); acc[1][1] = fmaf(a1, wv.y, acc[1][1]);
        acc[1][2] = fmaf(a1, wv.z, acc[1][2]); acc[1][3] = fmaf(a1, wv.w, acc[1][3]);
        acc[2][0] = fmaf(a2, wv.x, acc[2][0]); acc[2][1] = fmaf(a2, wv.y, acc[2][1]);
        acc[2][2] = fmaf(a2, wv.z, acc[2][2]); acc[2][3] = fmaf(a2, wv.w, acc[2][3]);
        acc[3][0] = fmaf(a3, wv.x, acc[3][0]); acc[3][1] = fmaf(a3, wv.y, acc[3][1]);
        acc[3][2] = fmaf(a3, wv.z, acc[3][2]); acc[3][3] = fmaf(a3, wv.w, acc[3][3]);
    }

    #pragma unroll
    for (int i = 0; i < 4; ++i) {
        int gn = node0 + ty * 4 + i;
        if (gn < n) {
            float dv = dis[gn];
            ushort4 o;
            o.x = f2b(acc[i][0] * dv); o.y = f2b(acc[i][1] * dv);
            o.z = f2b(acc[i][2] * dv); o.w = f2b(acc[i][3] * dv);
            ((ushort4*)(hw + (long long)gn * FOUT))[tx] = o;
        }
    }
}

// ------- CSR aggregation: y[d] = dis[d]*(sum hw'[src] + hw'[d]) + b; BN stats -------
template <int FOUT>
__global__ __launch_bounds__(256) void k_agg(const u16* __restrict__ hwb,
                                             const int* __restrict__ epack,
                                             const int* __restrict__ rp,
                                             const float* __restrict__ dis,
                                             const float* __restrict__ bias,
                                             float* __restrict__ y,
                                             float* __restrict__ stats, int n) {
    constexpr int LPN = FOUT / 8;          // lanes per node (uint4 = 8 bf16)
    constexpr int NPB = 256 / LPN;         // nodes per block
    constexpr int RS  = FOUT / 8;          // row stride in uint4
    __shared__ float ssum[FOUT], ssq[FOUT];
    for (int i = threadIdx.x; i < FOUT; i += 256) { ssum[i] = 0.f; ssq[i] = 0.f; }
    __syncthreads();
    const int local = threadIdx.x / LPN;
    const int fq = threadIdx.x % LPN;
    const uint4* hw4 = (const uint4*)hwb;
    float b8[8];
    #pragma unroll
    for (int i = 0; i < 8; ++i) b8[i] = bias[fq * 8 + i];
    float lsum[8] = {0,0,0,0,0,0,0,0}, lsq[8] = {0,0,0,0,0,0,0,0};

    for (long long base = (long long)blockIdx.x * NPB; base < n;
         base += (long long)gridDim.x * NPB) {
        int node = (int)base + local;
        if (node >= n) continue;
        int j0 = rp[node], j1 = rp[node + 1];
        float acc[8] = {0,0,0,0,0,0,0,0};
        int j = j0;
        for (; j + 4 <= j1; j += 4) {
            int s0 = epack[j + 0], s1 = epack[j + 1];
            int s2 = epack[j + 2], s3 = epack[j + 3];
            uint4 q0 = hw4[(long long)s0 * RS + fq];
            uint4 q1 = hw4[(long long)s1 * RS + fq];
            uint4 q2 = hw4[(long long)s2 * RS + fq];
            uint4 q3 = hw4[(long long)s3 * RS + fq];
            add8(q0, acc); add8(q1, acc); add8(q2, acc); add8(q3, acc);
        }
        for (; j < j1; ++j) {
            uint4 q = hw4[(long long)epack[j] * RS + fq];
            add8(q, acc);
        }
        uint4 qs = hw4[(long long)node * RS + fq];
        add8(qs, acc);                      // + hw'[d] (self term)
        float dv = dis[node];
        #pragma unroll
        for (int i = 0; i < 8; ++i) acc[i] = fmaf(dv, acc[i], b8[i]);
        float4* y4 = (float4*)y;
        long long o = (long long)node * (FOUT / 4) + fq * 2;
        y4[o]     = make_float4(acc[0], acc[1], acc[2], acc[3]);
        y4[o + 1] = make_float4(acc[4], acc[5], acc[6], acc[7]);
        #pragma unroll
        for (int i = 0; i < 8; ++i) {
            lsum[i] += acc[i];
            lsq[i] = fmaf(acc[i], acc[i], lsq[i]);
        }
    }
    #pragma unroll
    for (int i = 0; i < 8; ++i) {
        atomicAdd(&ssum[fq * 8 + i], lsum[i]);
        atomicAdd(&ssq[fq * 8 + i], lsq[i]);
    }
    __syncthreads();
    for (int i = threadIdx.x; i < FOUT; i += 256) {
        atomicAdd(&stats[i], ssum[i]);
        atomicAdd(&stats[64 + i], ssq[i]);
    }
}

// ---------------- BN apply + LeakyReLU (in place) ----------------
__global__ void k_bn(float* __restrict__ y, const float* __restrict__ stats,
                     const float* __restrict__ gma, const float* __restrict__ bta,
                     int n, int fout_shift) {
    long long tid = (long long)blockIdx.x * blockDim.x + threadIdx.x;
    if (tid >= ((long long)n << fout_shift)) return;
    int f = (int)(tid & ((1 << fout_shift) - 1));
    float inv_n = 1.0f / (float)n;
    float m = stats[f] * inv_n;
    float var = fmaxf(stats[64 + f] * inv_n - m * m, 0.f);
    float sc = rsqrtf(var + 1e-5f) * gma[f];
    float sh = bta[f] - m * sc;
    float v = y[tid] * sc + sh;
    y[tid] = v > 0.f ? v : 0.1f * v;
}

// ---------------- pooling: one block per graph (batch sorted) ----------------
__global__ void k_pool_graph(const float* __restrict__ h, const int* __restrict__ batch,
                             int n, float* __restrict__ psum, float* __restrict__ pmax,
                             float* __restrict__ pcnt) {
    const int g = blockIdx.x;
    __shared__ int s_lo, s_hi;
    if (threadIdx.x == 0) {
        int lo = 0, hi = n;
        while (lo < hi) { int mid = (lo + hi) >> 1; if (batch[mid] < g) lo = mid + 1; else hi = mid; }
        s_lo = lo;
        hi = n;
        while (lo < hi) { int mid = (lo + hi) >> 1; if (batch[mid] < g + 1) lo = mid + 1; else hi = mid; }
        s_hi = lo;
    }
    __syncthreads();
    const int start = s_lo, end = s_hi;
    float lsum = 0.f, lmax = -3.0e38f;
    for (long long idx = (long long)start * 16 + threadIdx.x; idx < (long long)end * 16; idx += blockDim.x) {
        float v = h[idx];
        lsum += v;
        lmax = fmaxf(lmax, v);
    }
    __shared__ float ss[256], sm[256];
    ss[threadIdx.x] = lsum; sm[threadIdx.x] = lmax;
    __syncthreads();
    for (int off = 128; off >= 16; off >>= 1) {
        if (threadIdx.x < off) {
            ss[threadIdx.x] += ss[threadIdx.x + off];
            sm[threadIdx.x] = fmaxf(sm[threadIdx.x], sm[threadIdx.x + off]);
        }
        __syncthreads();
    }
    if (threadIdx.x < 16) {
        psum[g * 16 + threadIdx.x] = ss[threadIdx.x];
        pmax[g * 16 + threadIdx.x] = sm[threadIdx.x];
    }
    if (threadIdx.x == 0) pcnt[g] = (float)(end - start);
}

// ---------------- head ----------------
__global__ void k_head(const float* __restrict__ psum, const float* __restrict__ pmax,
                       const float* __restrict__ pcnt,
                       const float* __restrict__ attn_w, const float* __restrict__ attn_b,
                       const float* __restrict__ fc1_w, const float* __restrict__ fc1_b,
                       const float* __restrict__ fc2_w, const float* __restrict__ fc2_b,
                       const float* __restrict__ out_w, const float* __restrict__ out_b,
                       float* __restrict__ out) {
    int g = threadIdx.x;
    if (g >= GG) return;
    float xs[16], xm[16], xx[16];
    float c = fmaxf(pcnt[g], 1.0f);
    for (int f = 0; f < 16; ++f) {
        xs[f] = psum[(g << 4) + f];
        xm[f] = xs[f] / c;
        xx[f] = pmax[(g << 4) + f];
    }
    float lg[3];
    for (int cI = 0; cI < 3; ++cI) {
        float a = attn_b[cI];
        for (int f = 0; f < 16; ++f) {
            a += xm[f] * attn_w[f * 3 + cI];
            a += xx[f] * attn_w[(16 + f) * 3 + cI];
            a += xs[f] * attn_w[(32 + f) * 3 + cI];
        }
        lg[cI] = a;
    }
    float mx = fmaxf(lg[0], fmaxf(lg[1], lg[2]));
    float e0 = expf(lg[0] - mx), e1 = expf(lg[1] - mx), e2 = expf(lg[2] - mx);
    float inv = 1.0f / (e0 + e1 + e2);
    float a0 = e0 * inv, a1 = e1 * inv, a2 = e2 * inv;
    float xg[16];
    for (int f = 0; f < 16; ++f) xg[f] = a0 * xm[f] + a1 * xx[f] + a2 * xs[f];
    float t1[16];
    for (int j = 0; j < 16; ++j) {
        float a = fc1_b[j];
        for (int k = 0; k < 16; ++k) a += xg[k] * fc1_w[k * 16 + j];
        t1[j] = a > 0.f ? a : 0.1f * a;
    }
    float t2[8];
    for (int j = 0; j < 8; ++j) {
        float a = fc2_b[j];
        for (int k = 0; k < 16; ++k) a += t1[k] * fc2_w[k * 8 + j];
        t2[j] = a > 0.f ? a : 0.1f * a;
    }
    float o = out_b[0];
    for (int k = 0; k < 8; ++k) o += t2[k] * out_w[k];
    o = 1.0f / (1.0f + expf(-o));
    out[g] = o;
}

extern "C" void kernel_launch(void* const* d_in, const int* in_sizes, int n_in,
                              void* d_out, int out_size, void* d_ws, size_t ws_size,
                              hipStream_t stream) {
    const float* x      = (const float*)d_in[0];
    const float* W1     = (const float*)d_in[1];  const float* b1   = (const float*)d_in[2];
    const float* W2     = (const float*)d_in[3];  const float* b2   = (const float*)d_in[4];
    const float* W3     = (const float*)d_in[5];  const float* b3   = (const float*)d_in[6];
    const float* g1     = (const float*)d_in[7];  const float* be1  = (const float*)d_in[8];
    const float* g2     = (const float*)d_in[9];  const float* be2  = (const float*)d_in[10];
    const float* g3     = (const float*)d_in[11]; const float* be3  = (const float*)d_in[12];
    const float* attn_w = (const float*)d_in[13]; const float* attn_b = (const float*)d_in[14];
    const float* fc1_w  = (const float*)d_in[15]; const float* fc1_b  = (const float*)d_in[16];
    const float* fc2_w  = (const float*)d_in[17]; const float* fc2_b  = (const float*)d_in[18];
    const float* out_w  = (const float*)d_in[19]; const float* out_b  = (const float*)d_in[20];
    const int* edge_index = (const int*)d_in[21];
    const int* batch      = (const int*)d_in[22];

    const int N = in_sizes[0] / 128;
    const int E = in_sizes[21] / 2;
    const int* srcp = edge_index;
    const int* dstp = edge_index + E;
    const int nb = (N + 255) / 256;

    char* ws = (char*)d_ws;
    float* dis    = (float*)(ws);                 // N f32
    int*   cnt    = (int*)(ws + 0x80000);         // N int (reused as cursor)
    int*   rp     = (int*)(ws + 0x100000);        // N+1 int
    int*   bsum   = (int*)(ws + 0x180000);        // <=512 int
    float* stats  = (float*)(ws + 0x182000);      // 128 f32
    float* psum   = stats + 128;
    float* pmax   = psum + GG * 16;
    float* pcnt   = pmax + GG * 16;
    int*   epack  = (int*)(ws + 0x190000);        // E * 4B (src only)
    float* buf1   = (float*)(ws + 0x190000 + (size_t)E * 4);  // N*64 f32 (y / h)
    u16*   hwb    = (u16*)(buf1 + (size_t)N * 64);            // N*64 bf16 (hw')

    // ---- CSR build ----
    hipMemsetAsync(cnt, 0, (size_t)N * 4, stream);
    k_hist<<<(E + 255) / 256, 256, 0, stream>>>(dstp, cnt, E);
    k_dis<<<nb, 256, 0, stream>>>(cnt, dis, N);
    k_scanA<<<nb, 256, 0, stream>>>(cnt, rp, bsum, N);
    k_scanB<<<1, 512, 0, stream>>>(bsum, nb);
    k_scanC<<<nb, 256, 0, stream>>>(rp, bsum, cnt, N, E);
    k_scatter<<<(E + 255) / 256, 256, 0, stream>>>(srcp, dstp, cnt, epack, E);

    // exact-cover agg grids: one node-group pass per block
    const int gr1 = (N + 31) / 32;    // FOUT=64: NPB=32
    const int gr2 = (N + 63) / 64;    // FOUT=32: NPB=64
    const int gr3 = (N + 127) / 128;  // FOUT=16: NPB=128

    // ---- layer 1 ----
    k_mm<128, 64><<<(N + 63) / 64, 256, 0, stream>>>(x, W1, dis, hwb, N);
    hipMemsetAsync(stats, 0, 512, stream);
    k_agg<64><<<gr1, 256, 0, stream>>>(hwb, epack, rp, dis, b1, buf1, stats, N);
    k_bn<<<(unsigned)(((long long)N * 64 + 255) / 256), 256, 0, stream>>>(
        buf1, stats, g1, be1, N, 6);

    // ---- layer 2 ----
    k_mm<64, 32><<<(N + 127) / 128, 256, 0, stream>>>(buf1, W2, dis, hwb, N);
    hipMemsetAsync(stats, 0, 512, stream);
    k_agg<32><<<gr2, 256, 0, stream>>>(hwb, epack, rp, dis, b2, buf1, stats, N);
    k_bn<<<(unsigned)(((long long)N * 32 + 255) / 256), 256, 0, stream>>>(
        buf1, stats, g2, be2, N, 5);

    // ---- layer 3 ----
    k_mm<32, 16><<<(N + 255) / 256, 256, 0, stream>>>(buf1, W3, dis, hwb, N);
    hipMemsetAsync(stats, 0, 512, stream);
    k_agg<16><<<gr3, 256, 0, stream>>>(hwb, epack, rp, dis, b3, buf1, stats, N);
    k_bn<<<(unsigned)(((long long)N * 16 + 255) / 256), 256, 0, stream>>>(
        buf1, stats, g3, be3, N, 4);

    // ---- pooling + head ----
    k_pool_graph<<<GG, 256, 0, stream>>>(buf1, batch, N, psum, pmax, pcnt);
    k_head<<<1, 64, 0, stream>>>(psum, pmax, pcnt, attn_w, attn_b,
                                 fc1_w, fc1_b, fc2_w, fc2_b, out_w, out_b,
                                 (float*)d_out);
}

// Round 10
// 649.629 us; speedup vs baseline: 1.0652x; 1.0652x over previous
//
#include <hip/hip_runtime.h>

#define GG 64   // num_graphs (fixed by problem)
typedef unsigned long long ull;
typedef unsigned short u16;

__device__ __forceinline__ u16 f2b(float x) {          // fp32 -> bf16 (RN-even)
    unsigned u = __float_as_uint(x);
    return (u16)((u + 0x7FFFu + ((u >> 16) & 1u)) >> 16);
}

// unpack uint4 (8 bf16) and add into acc[8]
__device__ __forceinline__ void add8(const uint4 q, float* acc) {
    acc[0] += __uint_as_float(q.x << 16);
    acc[1] += __uint_as_float(q.x & 0xFFFF0000u);
    acc[2] += __uint_as_float(q.y << 16);
    acc[3] += __uint_as_float(q.y & 0xFFFF0000u);
    acc[4] += __uint_as_float(q.z << 16);
    acc[5] += __uint_as_float(q.z & 0xFFFF0000u);
    acc[6] += __uint_as_float(q.w << 16);
    acc[7] += __uint_as_float(q.w & 0xFFFF0000u);
}

// ---------------- CSR build ----------------
__global__ void k_hist(const int* __restrict__ dst, int* __restrict__ cnt, int E) {
    int e = blockIdx.x * blockDim.x + threadIdx.x;
    if (e < E) atomicAdd(&cnt[dst[e]], 1);
}

__global__ void k_dis(const int* __restrict__ cnt, float* __restrict__ dis, int n) {
    int i = blockIdx.x * blockDim.x + threadIdx.x;
    if (i < n) dis[i] = rsqrtf((float)cnt[i] + 1.0f);
}

__global__ void k_scanA(const int* __restrict__ cnt, int* __restrict__ rp,
                        int* __restrict__ bsum, int n) {
    __shared__ int s[256];
    int i = blockIdx.x * 256 + threadIdx.x;
    int v = (i < n) ? cnt[i] : 0;
    s[threadIdx.x] = v;
    __syncthreads();
    for (int off = 1; off < 256; off <<= 1) {
        int t = (threadIdx.x >= off) ? s[threadIdx.x - off] : 0;
        __syncthreads();
        s[threadIdx.x] += t;
        __syncthreads();
    }
    if (i < n) rp[i] = s[threadIdx.x] - v;
    if (threadIdx.x == 255) bsum[blockIdx.x] = s[255];
}

__global__ void k_scanB(int* __restrict__ bsum, int nb) {
    __shared__ int s[512];
    int v = (threadIdx.x < nb) ? bsum[threadIdx.x] : 0;
    s[threadIdx.x] = v;
    __syncthreads();
    for (int off = 1; off < 512; off <<= 1) {
        int t = (threadIdx.x >= off) ? s[threadIdx.x - off] : 0;
        __syncthreads();
        s[threadIdx.x] += t;
        __syncthreads();
    }
    if (threadIdx.x < nb) bsum[threadIdx.x] = s[threadIdx.x] - v;
}

__global__ void k_scanC(int* __restrict__ rp, const int* __restrict__ bsum,
                        int* __restrict__ cursor, int n, int E) {
    int i = blockIdx.x * 256 + threadIdx.x;
    if (i < n) {
        int r = rp[i] + bsum[blockIdx.x];
        rp[i] = r;
        cursor[i] = r;
    }
    if (i == 0) rp[n] = E;
}

// scatter: 8-byte records (src in low word) — measured faster than 4B stores (R8 vs R9)
__global__ void k_scatter(const int* __restrict__ src, const int* __restrict__ dst,
                          int* __restrict__ cursor, ull* __restrict__ epack, int E) {
    int e = blockIdx.x * blockDim.x + threadIdx.x;
    if (e >= E) return;
    int s = src[e], d = dst[e];
    int pos = atomicAdd(&cursor[d], 1);
    epack[pos] = (ull)(unsigned)s;
}

// ---- tiled GEMM (+optional fused BN-apply+LeakyReLU on input) + dis-fold output ----
// hwb[n,FOUT](bf16) = lrelu(bn(h)) @ W * dis[n]   (BN==true)
template <int FIN, int FOUT, bool BN>
__global__ __launch_bounds__(256) void k_mm(const float* __restrict__ h,
                                            const float* __restrict__ W,
                                            const float* __restrict__ dis,
                                            const float* __restrict__ stats,
                                            const float* __restrict__ gma,
                                            const float* __restrict__ bta,
                                            u16* __restrict__ hw, int n) {
    constexpr int FX  = FOUT / 4;
    constexpr int TY  = 256 / FX;
    constexpr int NT  = TY * 4;
    constexpr int LDA = FIN + ((FOUT == 64) ? 2 : 1);
    __shared__ float sA[NT * LDA];
    __shared__ float sW[FIN * FOUT];
    __shared__ float sSc[FIN], sSh[FIN];

    if (BN && threadIdx.x < FIN) {
        int f = threadIdx.x;
        float inv_n = 1.0f / (float)n;
        float m = stats[f] * inv_n;
        float var = fmaxf(stats[64 + f] * inv_n - m * m, 0.f);
        float sc = rsqrtf(var + 1e-5f) * gma[f];
        sSc[f] = sc;
        sSh[f] = bta[f] - m * sc;
    }
    for (int i = threadIdx.x; i < FIN * FOUT / 4; i += 256)
        ((float4*)sW)[i] = ((const float4*)W)[i];
    if (BN) __syncthreads();

    const int node0 = blockIdx.x * NT;
    constexpr int LD4 = NT * FIN / 4 / 256;
    #pragma unroll
    for (int i = 0; i < LD4; ++i) {
        int idx4 = i * 256 + threadIdx.x;
        int row = idx4 / (FIN / 4);
        int c4  = idx4 % (FIN / 4);
        int gn  = node0 + row;
        float4 v = make_float4(0.f, 0.f, 0.f, 0.f);
        if (gn < n) v = ((const float4*)(h + (long long)gn * FIN))[c4];
        if (BN) {
            int f = c4 * 4;
            float t;
            t = fmaf(v.x, sSc[f + 0], sSh[f + 0]); v.x = t > 0.f ? t : 0.1f * t;
            t = fmaf(v.y, sSc[f + 1], sSh[f + 1]); v.y = t > 0.f ? t : 0.1f * t;
            t = fmaf(v.z, sSc[f + 2], sSh[f + 2]); v.z = t > 0.f ? t : 0.1f * t;
            t = fmaf(v.w, sSc[f + 3], sSh[f + 3]); v.w = t > 0.f ? t : 0.1f * t;
        }
        float* p = &sA[row * LDA + c4 * 4];
        p[0] = v.x; p[1] = v.y; p[2] = v.z; p[3] = v.w;
    }
    __syncthreads();

    const int tx = threadIdx.x % FX;
    const int ty = threadIdx.x / FX;
    float acc[4][4];
    #pragma unroll
    for (int i = 0; i < 4; ++i)
        #pragma unroll
        for (int j = 0; j < 4; ++j) acc[i][j] = 0.f;

    #pragma unroll 8
    for (int k = 0; k < FIN; ++k) {
        float4 wv = *((const float4*)&sW[k * FOUT + tx * 4]);
        float a0 = sA[(ty * 4 + 0) * LDA + k];
        float a1 = sA[(ty * 4 + 1) * LDA + k];
        float a2 = sA[(ty * 4 + 2) * LDA + k];
        float a3 = sA[(ty * 4 + 3) * LDA + k];
        acc[0][0] = fmaf(a0, wv.x, acc[0][0]); acc[0][1] = fmaf(a0, wv.y, acc[0][1]);
        acc[0][2] = fmaf(a0, wv.z, acc[0][2]); acc[0][3] = fmaf(a0, wv.w, acc[0][3]);
        acc[1][0] = fmaf(a1, wv.x, acc[1][0]); acc[1][1] = fmaf(a1, wv.y, acc[1][1]);
        acc[1][2] = fmaf(a1, wv.z, acc[1][2]); acc[1][3] = fmaf(a1, wv.w, acc[1][3]);
        acc[2][0] = fmaf(a2, wv.x, acc[2][0]); acc[2][1] = fmaf(a2, wv.y, acc[2][1]);
        acc[2][2] = fmaf(a2, wv.z, acc[2][2]); acc[2][3] = fmaf(a2, wv.w, acc[2][3]);
        acc[3][0] = fmaf(a3, wv.x, acc[3][0]); acc[3][1] = fmaf(a3, wv.y, acc[3][1]);
        acc[3][2] = fmaf(a3, wv.z, acc[3][2]); acc[3][3] = fmaf(a3, wv.w, acc[3][3]);
    }

    #pragma unroll
    for (int i = 0; i < 4; ++i) {
        int gn = node0 + ty * 4 + i;
        if (gn < n) {
            float dv = dis[gn];
            ushort4 o;
            o.x = f2b(acc[i][0] * dv); o.y = f2b(acc[i][1] * dv);
            o.z = f2b(acc[i][2] * dv); o.w = f2b(acc[i][3] * dv);
            ((ushort4*)(hw + (long long)gn * FOUT))[tx] = o;
        }
    }
}

// ------- CSR aggregation: y[d] = dis[d]*(sum hw'[src] + hw'[d]) + b; BN stats -------
template <int FOUT>
__global__ __launch_bounds__(256) void k_agg(const u16* __restrict__ hwb,
                                             const ull* __restrict__ epack,
                                             const int* __restrict__ rp,
                                             const float* __restrict__ dis,
                                             const float* __restrict__ bias,
                                             float* __restrict__ y,
                                             float* __restrict__ stats, int n) {
    constexpr int LPN = FOUT / 8;          // lanes per node (uint4 = 8 bf16)
    constexpr int NPB = 256 / LPN;         // nodes per block
    constexpr int RS  = FOUT / 8;          // row stride in uint4
    __shared__ float ssum[FOUT], ssq[FOUT];
    for (int i = threadIdx.x; i < FOUT; i += 256) { ssum[i] = 0.f; ssq[i] = 0.f; }
    __syncthreads();
    const int local = threadIdx.x / LPN;
    const int fq = threadIdx.x % LPN;
    const uint4* hw4 = (const uint4*)hwb;
    float b8[8];
    #pragma unroll
    for (int i = 0; i < 8; ++i) b8[i] = bias[fq * 8 + i];
    float lsum[8] = {0,0,0,0,0,0,0,0}, lsq[8] = {0,0,0,0,0,0,0,0};

    int node = blockIdx.x * NPB + local;
    if (node < n) {
        int j0 = rp[node], j1 = rp[node + 1];
        float acc[8] = {0,0,0,0,0,0,0,0};
        int j = j0;
        for (; j + 4 <= j1; j += 4) {
            int s0 = (int)(unsigned)epack[j + 0];
            int s1 = (int)(unsigned)epack[j + 1];
            int s2 = (int)(unsigned)epack[j + 2];
            int s3 = (int)(unsigned)epack[j + 3];
            uint4 q0 = hw4[(long long)s0 * RS + fq];
            uint4 q1 = hw4[(long long)s1 * RS + fq];
            uint4 q2 = hw4[(long long)s2 * RS + fq];
            uint4 q3 = hw4[(long long)s3 * RS + fq];
            add8(q0, acc); add8(q1, acc); add8(q2, acc); add8(q3, acc);
        }
        for (; j < j1; ++j) {
            uint4 q = hw4[(long long)(unsigned)epack[j] * RS + fq];
            add8(q, acc);
        }
        uint4 qs = hw4[(long long)node * RS + fq];
        add8(qs, acc);                      // + hw'[d] (self term)
        float dv = dis[node];
        #pragma unroll
        for (int i = 0; i < 8; ++i) acc[i] = fmaf(dv, acc[i], b8[i]);
        float4* y4 = (float4*)y;
        long long o = (long long)node * (FOUT / 4) + fq * 2;
        y4[o]     = make_float4(acc[0], acc[1], acc[2], acc[3]);
        y4[o + 1] = make_float4(acc[4], acc[5], acc[6], acc[7]);
        #pragma unroll
        for (int i = 0; i < 8; ++i) {
            lsum[i] += acc[i];
            lsq[i] = fmaf(acc[i], acc[i], lsq[i]);
        }
    }
    #pragma unroll
    for (int i = 0; i < 8; ++i) {
        atomicAdd(&ssum[fq * 8 + i], lsum[i]);
        atomicAdd(&ssq[fq * 8 + i], lsq[i]);
    }
    __syncthreads();
    for (int i = threadIdx.x; i < FOUT; i += 256) {
        atomicAdd(&stats[i], ssum[i]);
        atomicAdd(&stats[64 + i], ssq[i]);
    }
}

// -------- pooling (fused BN-apply+LeakyReLU on layer-3 y): one block per graph ------
__global__ void k_pool_graph(const float* __restrict__ yraw, const int* __restrict__ batch,
                             const float* __restrict__ stats, const float* __restrict__ gma,
                             const float* __restrict__ bta, int n,
                             float* __restrict__ psum, float* __restrict__ pmax,
                             float* __restrict__ pcnt) {
    const int g = blockIdx.x;
    const int f = threadIdx.x & 15;
    float inv_n = 1.0f / (float)n;
    float m = stats[f] * inv_n;
    float var = fmaxf(stats[64 + f] * inv_n - m * m, 0.f);
    float sc = rsqrtf(var + 1e-5f) * gma[f];
    float sh = bta[f] - m * sc;

    __shared__ int s_lo, s_hi;
    if (threadIdx.x == 0) {
        int lo = 0, hi = n;
        while (lo < hi) { int mid = (lo + hi) >> 1; if (batch[mid] < g) lo = mid + 1; else hi = mid; }
        s_lo = lo;
        hi = n;
        while (lo < hi) { int mid = (lo + hi) >> 1; if (batch[mid] < g + 1) lo = mid + 1; else hi = mid; }
        s_hi = lo;
    }
    __syncthreads();
    const int start = s_lo, end = s_hi;
    float lsum = 0.f, lmax = -3.0e38f;
    for (long long idx = (long long)start * 16 + threadIdx.x; idx < (long long)end * 16; idx += blockDim.x) {
        float t = fmaf(yraw[idx], sc, sh);
        float v = t > 0.f ? t : 0.1f * t;
        lsum += v;
        lmax = fmaxf(lmax, v);
    }
    __shared__ float ss[256], sm[256];
    ss[threadIdx.x] = lsum; sm[threadIdx.x] = lmax;
    __syncthreads();
    for (int off = 128; off >= 16; off >>= 1) {
        if (threadIdx.x < off) {
            ss[threadIdx.x] += ss[threadIdx.x + off];
            sm[threadIdx.x] = fmaxf(sm[threadIdx.x], sm[threadIdx.x + off]);
        }
        __syncthreads();
    }
    if (threadIdx.x < 16) {
        psum[g * 16 + threadIdx.x] = ss[threadIdx.x];
        pmax[g * 16 + threadIdx.x] = sm[threadIdx.x];
    }
    if (threadIdx.x == 0) pcnt[g] = (float)(end - start);
}

// ---------------- head ----------------
__global__ void k_head(const float* __restrict__ psum, const float* __restrict__ pmax,
                       const float* __restrict__ pcnt,
                       const float* __restrict__ attn_w, const float* __restrict__ attn_b,
                       const float* __restrict__ fc1_w, const float* __restrict__ fc1_b,
                       const float* __restrict__ fc2_w, const float* __restrict__ fc2_b,
                       const float* __restrict__ out_w, const float* __restrict__ out_b,
                       float* __restrict__ out) {
    int g = threadIdx.x;
    if (g >= GG) return;
    float xs[16], xm[16], xx[16];
    float c = fmaxf(pcnt[g], 1.0f);
    for (int f = 0; f < 16; ++f) {
        xs[f] = psum[(g << 4) + f];
        xm[f] = xs[f] / c;
        xx[f] = pmax[(g << 4) + f];
    }
    float lg[3];
    for (int cI = 0; cI < 3; ++cI) {
        float a = attn_b[cI];
        for (int f = 0; f < 16; ++f) {
            a += xm[f] * attn_w[f * 3 + cI];
            a += xx[f] * attn_w[(16 + f) * 3 + cI];
            a += xs[f] * attn_w[(32 + f) * 3 + cI];
        }
        lg[cI] = a;
    }
    float mx = fmaxf(lg[0], fmaxf(lg[1], lg[2]));
    float e0 = expf(lg[0] - mx), e1 = expf(lg[1] - mx), e2 = expf(lg[2] - mx);
    float inv = 1.0f / (e0 + e1 + e2);
    float a0 = e0 * inv, a1 = e1 * inv, a2 = e2 * inv;
    float xg[16];
    for (int f = 0; f < 16; ++f) xg[f] = a0 * xm[f] + a1 * xx[f] + a2 * xs[f];
    float t1[16];
    for (int j = 0; j < 16; ++j) {
        float a = fc1_b[j];
        for (int k = 0; k < 16; ++k) a += xg[k] * fc1_w[k * 16 + j];
        t1[j] = a > 0.f ? a : 0.1f * a;
    }
    float t2[8];
    for (int j = 0; j < 8; ++j) {
        float a = fc2_b[j];
        for (int k = 0; k < 16; ++k) a += t1[k] * fc2_w[k * 8 + j];
        t2[j] = a > 0.f ? a : 0.1f * a;
    }
    float o = out_b[0];
    for (int k = 0; k < 8; ++k) o += t2[k] * out_w[k];
    o = 1.0f / (1.0f + expf(-o));
    out[g] = o;
}

extern "C" void kernel_launch(void* const* d_in, const int* in_sizes, int n_in,
                              void* d_out, int out_size, void* d_ws, size_t ws_size,
                              hipStream_t stream) {
    const float* x      = (const float*)d_in[0];
    const float* W1     = (const float*)d_in[1];  const float* b1   = (const float*)d_in[2];
    const float* W2     = (const float*)d_in[3];  const float* b2   = (const float*)d_in[4];
    const float* W3     = (const float*)d_in[5];  const float* b3   = (const float*)d_in[6];
    const float* g1     = (const float*)d_in[7];  const float* be1  = (const float*)d_in[8];
    const float* g2     = (const float*)d_in[9];  const float* be2  = (const float*)d_in[10];
    const float* g3     = (const float*)d_in[11]; const float* be3  = (const float*)d_in[12];
    const float* attn_w = (const float*)d_in[13]; const float* attn_b = (const float*)d_in[14];
    const float* fc1_w  = (const float*)d_in[15]; const float* fc1_b  = (const float*)d_in[16];
    const float* fc2_w  = (const float*)d_in[17]; const float* fc2_b  = (const float*)d_in[18];
    const float* out_w  = (const float*)d_in[19]; const float* out_b  = (const float*)d_in[20];
    const int* edge_index = (const int*)d_in[21];
    const int* batch      = (const int*)d_in[22];

    const int N = in_sizes[0] / 128;
    const int E = in_sizes[21] / 2;
    const int* srcp = edge_index;
    const int* dstp = edge_index + E;
    const int nb = (N + 255) / 256;

    char* ws = (char*)d_ws;
    float* dis    = (float*)(ws);                 // N f32
    int*   cnt    = (int*)(ws + 0x80000);         // N int (reused as cursor)
    int*   rp     = (int*)(ws + 0x100000);        // N+1 int
    int*   bsum   = (int*)(ws + 0x180000);        // <=512 int
    float* stats1 = (float*)(ws + 0x182000);      // 128 f32 per layer, 3 layers
    float* stats2 = stats1 + 128;
    float* stats3 = stats2 + 128;
    float* psum   = stats3 + 128;
    float* pmax   = psum + GG * 16;
    float* pcnt   = pmax + GG * 16;
    ull*   epack  = (ull*)(ws + 0x190000);        // E * 8B
    float* buf1   = (float*)(ws + 0x190000 + (size_t)E * 8);  // N*64 f32 (y)
    u16*   hwb    = (u16*)(buf1 + (size_t)N * 64);            // N*64 bf16 (hw')

    // ---- CSR build ----
    hipMemsetAsync(cnt, 0, (size_t)N * 4, stream);
    k_hist<<<(E + 255) / 256, 256, 0, stream>>>(dstp, cnt, E);
    k_dis<<<nb, 256, 0, stream>>>(cnt, dis, N);
    k_scanA<<<nb, 256, 0, stream>>>(cnt, rp, bsum, N);
    k_scanB<<<1, 512, 0, stream>>>(bsum, nb);
    k_scanC<<<nb, 256, 0, stream>>>(rp, bsum, cnt, N, E);
    k_scatter<<<(E + 255) / 256, 256, 0, stream>>>(srcp, dstp, cnt, epack, E);
    hipMemsetAsync(stats1, 0, 3 * 512, stream);

    // exact-cover agg grids
    const int gr1 = (N + 31) / 32;    // FOUT=64: NPB=32
    const int gr2 = (N + 63) / 64;    // FOUT=32: NPB=64
    const int gr3 = (N + 127) / 128;  // FOUT=16: NPB=128

    // ---- layer 1 (no BN on input) ----
    k_mm<128, 64, false><<<(N + 63) / 64, 256, 0, stream>>>(
        x, W1, dis, nullptr, nullptr, nullptr, hwb, N);
    k_agg<64><<<gr1, 256, 0, stream>>>(hwb, epack, rp, dis, b1, buf1, stats1, N);

    // ---- layer 2 (BN1+lrelu fused into staging) ----
    k_mm<64, 32, true><<<(N + 127) / 128, 256, 0, stream>>>(
        buf1, W2, dis, stats1, g1, be1, hwb, N);
    k_agg<32><<<gr2, 256, 0, stream>>>(hwb, epack, rp, dis, b2, buf1, stats2, N);

    // ---- layer 3 (BN2+lrelu fused) ----
    k_mm<32, 16, true><<<(N + 255) / 256, 256, 0, stream>>>(
        buf1, W3, dis, stats2, g2, be2, hwb, N);
    k_agg<16><<<gr3, 256, 0, stream>>>(hwb, epack, rp, dis, b3, buf1, stats3, N);

    // ---- pooling (BN3+lrelu fused) + head ----
    k_pool_graph<<<GG, 256, 0, stream>>>(buf1, batch, stats3, g3, be3, N, psum, pmax, pcnt);
    k_head<<<1, 64, 0, stream>>>(psum, pmax, pcnt, attn_w, attn_b,
                                 fc1_w, fc1_b, fc2_w, fc2_b, out_w, out_b,
                                 (float*)d_out);
}

// Round 11
// 598.849 us; speedup vs baseline: 1.1555x; 1.0848x over previous
//
#include <hip/hip_runtime.h>

#define GG 64   // num_graphs (fixed by problem)
typedef unsigned long long ull;
typedef unsigned short u16;

__device__ __forceinline__ u16 f2b(float x) {          // fp32 -> bf16 (RN-even)
    unsigned u = __float_as_uint(x);
    return (u16)((u + 0x7FFFu + ((u >> 16) & 1u)) >> 16);
}

// unpack uint4 (8 bf16) and add into acc[8]
__device__ __forceinline__ void add8(const uint4 q, float* acc) {
    acc[0] += __uint_as_float(q.x << 16);
    acc[1] += __uint_as_float(q.x & 0xFFFF0000u);
    acc[2] += __uint_as_float(q.y << 16);
    acc[3] += __uint_as_float(q.y & 0xFFFF0000u);
    acc[4] += __uint_as_float(q.z << 16);
    acc[5] += __uint_as_float(q.z & 0xFFFF0000u);
    acc[6] += __uint_as_float(q.w << 16);
    acc[7] += __uint_as_float(q.w & 0xFFFF0000u);
}

// ---------------- CSR build ----------------
__global__ void k_hist(const int* __restrict__ dst, int* __restrict__ cnt, int E) {
    int e = blockIdx.x * blockDim.x + threadIdx.x;
    if (e < E) atomicAdd(&cnt[dst[e]], 1);
}

__global__ void k_dis(const int* __restrict__ cnt, float* __restrict__ dis, int n) {
    int i = blockIdx.x * blockDim.x + threadIdx.x;
    if (i < n) dis[i] = rsqrtf((float)cnt[i] + 1.0f);
}

__global__ void k_scanA(const int* __restrict__ cnt, int* __restrict__ rp,
                        int* __restrict__ bsum, int n) {
    __shared__ int s[256];
    int i = blockIdx.x * 256 + threadIdx.x;
    int v = (i < n) ? cnt[i] : 0;
    s[threadIdx.x] = v;
    __syncthreads();
    for (int off = 1; off < 256; off <<= 1) {
        int t = (threadIdx.x >= off) ? s[threadIdx.x - off] : 0;
        __syncthreads();
        s[threadIdx.x] += t;
        __syncthreads();
    }
    if (i < n) rp[i] = s[threadIdx.x] - v;
    if (threadIdx.x == 255) bsum[blockIdx.x] = s[255];
}

__global__ void k_scanB(int* __restrict__ bsum, int nb) {
    __shared__ int s[512];
    int v = (threadIdx.x < nb) ? bsum[threadIdx.x] : 0;
    s[threadIdx.x] = v;
    __syncthreads();
    for (int off = 1; off < 512; off <<= 1) {
        int t = (threadIdx.x >= off) ? s[threadIdx.x - off] : 0;
        __syncthreads();
        s[threadIdx.x] += t;
        __syncthreads();
    }
    if (threadIdx.x < nb) bsum[threadIdx.x] = s[threadIdx.x] - v;
}

__global__ void k_scanC(int* __restrict__ rp, const int* __restrict__ bsum,
                        int* __restrict__ cursor, int n, int E) {
    int i = blockIdx.x * 256 + threadIdx.x;
    if (i < n) {
        int r = rp[i] + bsum[blockIdx.x];
        rp[i] = r;
        cursor[i] = r;
    }
    if (i == 0) rp[n] = E;
}

// XCD-partitioned scatter: block b handles dst range (b&7); all stores to a given
// epack line then come from one XCD -> line merges in that XCD's L2 (1.6MB slice
// fits in 4MB) -> single full-line writeback instead of ~8 partial ones.
__global__ __launch_bounds__(256) void k_scatter(const int* __restrict__ src,
                                                 const int* __restrict__ dst,
                                                 int* __restrict__ cursor,
                                                 ull* __restrict__ epack, int E, int n) {
    const int part = blockIdx.x & 7;
    const int nblk = gridDim.x >> 3;
    const int bser = blockIdx.x >> 3;
    const int lo = (int)(((long long)part * n) >> 3);
    const int hi = (part == 7) ? n : (int)(((long long)(part + 1) * n) >> 3);
    for (int e = bser * 256 + threadIdx.x; e < E; e += nblk * 256) {
        int d = dst[e];
        if (d >= lo && d < hi) {
            int s = src[e];
            int pos = atomicAdd(&cursor[d], 1);
            epack[pos] = (ull)(unsigned)s;
        }
    }
}

// ---- tiled GEMM (+optional fused BN-apply+LeakyReLU on input) + dis-fold output ----
template <int FIN, int FOUT, bool BN>
__global__ __launch_bounds__(256) void k_mm(const float* __restrict__ h,
                                            const float* __restrict__ W,
                                            const float* __restrict__ dis,
                                            const float* __restrict__ stats,
                                            const float* __restrict__ gma,
                                            const float* __restrict__ bta,
                                            u16* __restrict__ hw, int n) {
    constexpr int FX  = FOUT / 4;
    constexpr int TY  = 256 / FX;
    constexpr int NT  = TY * 4;
    constexpr int LDA = FIN + ((FOUT == 64) ? 2 : 1);
    __shared__ float sA[NT * LDA];
    __shared__ float sW[FIN * FOUT];
    __shared__ float sSc[FIN], sSh[FIN];

    if (BN && threadIdx.x < FIN) {
        int f = threadIdx.x;
        float inv_n = 1.0f / (float)n;
        float m = stats[f] * inv_n;
        float var = fmaxf(stats[64 + f] * inv_n - m * m, 0.f);
        float sc = rsqrtf(var + 1e-5f) * gma[f];
        sSc[f] = sc;
        sSh[f] = bta[f] - m * sc;
    }
    for (int i = threadIdx.x; i < FIN * FOUT / 4; i += 256)
        ((float4*)sW)[i] = ((const float4*)W)[i];
    if (BN) __syncthreads();

    const int node0 = blockIdx.x * NT;
    constexpr int LD4 = NT * FIN / 4 / 256;
    #pragma unroll
    for (int i = 0; i < LD4; ++i) {
        int idx4 = i * 256 + threadIdx.x;
        int row = idx4 / (FIN / 4);
        int c4  = idx4 % (FIN / 4);
        int gn  = node0 + row;
        float4 v = make_float4(0.f, 0.f, 0.f, 0.f);
        if (gn < n) v = ((const float4*)(h + (long long)gn * FIN))[c4];
        if (BN) {
            int f = c4 * 4;
            float t;
            t = fmaf(v.x, sSc[f + 0], sSh[f + 0]); v.x = t > 0.f ? t : 0.1f * t;
            t = fmaf(v.y, sSc[f + 1], sSh[f + 1]); v.y = t > 0.f ? t : 0.1f * t;
            t = fmaf(v.z, sSc[f + 2], sSh[f + 2]); v.z = t > 0.f ? t : 0.1f * t;
            t = fmaf(v.w, sSc[f + 3], sSh[f + 3]); v.w = t > 0.f ? t : 0.1f * t;
        }
        float* p = &sA[row * LDA + c4 * 4];
        p[0] = v.x; p[1] = v.y; p[2] = v.z; p[3] = v.w;
    }
    __syncthreads();

    const int tx = threadIdx.x % FX;
    const int ty = threadIdx.x / FX;
    float acc[4][4];
    #pragma unroll
    for (int i = 0; i < 4; ++i)
        #pragma unroll
        for (int j = 0; j < 4; ++j) acc[i][j] = 0.f;

    #pragma unroll 8
    for (int k = 0; k < FIN; ++k) {
        float4 wv = *((const float4*)&sW[k * FOUT + tx * 4]);
        float a0 = sA[(ty * 4 + 0) * LDA + k];
        float a1 = sA[(ty * 4 + 1) * LDA + k];
        float a2 = sA[(ty * 4 + 2) * LDA + k];
        float a3 = sA[(ty * 4 + 3) * LDA + k];
        acc[0][0] = fmaf(a0, wv.x, acc[0][0]); acc[0][1] = fmaf(a0, wv.y, acc[0][1]);
        acc[0][2] = fmaf(a0, wv.z, acc[0][2]); acc[0][3] = fmaf(a0, wv.w, acc[0][3]);
        acc[1][0] = fmaf(a1, wv.x, acc[1][0]); acc[1][1] = fmaf(a1, wv.y, acc[1][1]);
        acc[1][2] = fmaf(a1, wv.z, acc[1][2]); acc[1][3] = fmaf(a1, wv.w, acc[1][3]);
        acc[2][0] = fmaf(a2, wv.x, acc[2][0]); acc[2][1] = fmaf(a2, wv.y, acc[2][1]);
        acc[2][2] = fmaf(a2, wv.z, acc[2][2]); acc[2][3] = fmaf(a2, wv.w, acc[2][3]);
        acc[3][0] = fmaf(a3, wv.x, acc[3][0]); acc[3][1] = fmaf(a3, wv.y, acc[3][1]);
        acc[3][2] = fmaf(a3, wv.z, acc[3][2]); acc[3][3] = fmaf(a3, wv.w, acc[3][3]);
    }

    #pragma unroll
    for (int i = 0; i < 4; ++i) {
        int gn = node0 + ty * 4 + i;
        if (gn < n) {
            float dv = dis[gn];
            ushort4 o;
            o.x = f2b(acc[i][0] * dv); o.y = f2b(acc[i][1] * dv);
            o.z = f2b(acc[i][2] * dv); o.w = f2b(acc[i][3] * dv);
            ((ushort4*)(hw + (long long)gn * FOUT))[tx] = o;
        }
    }
}

// ------- CSR aggregation: y[d] = dis[d]*(sum hw'[src] + hw'[d]) + b; BN stats -------
template <int FOUT>
__global__ __launch_bounds__(256) void k_agg(const u16* __restrict__ hwb,
                                             const ull* __restrict__ epack,
                                             const int* __restrict__ rp,
                                             const float* __restrict__ dis,
                                             const float* __restrict__ bias,
                                             float* __restrict__ y,
                                             float* __restrict__ stats, int n) {
    constexpr int LPN = FOUT / 8;          // lanes per node (uint4 = 8 bf16)
    constexpr int NPB = 256 / LPN;         // nodes per block
    constexpr int RS  = FOUT / 8;          // row stride in uint4
    __shared__ float ssum[FOUT], ssq[FOUT];
    for (int i = threadIdx.x; i < FOUT; i += 256) { ssum[i] = 0.f; ssq[i] = 0.f; }
    __syncthreads();
    const int local = threadIdx.x / LPN;
    const int fq = threadIdx.x % LPN;
    const uint4* hw4 = (const uint4*)hwb;
    float b8[8];
    #pragma unroll
    for (int i = 0; i < 8; ++i) b8[i] = bias[fq * 8 + i];
    float lsum[8] = {0,0,0,0,0,0,0,0}, lsq[8] = {0,0,0,0,0,0,0,0};

    int node = blockIdx.x * NPB + local;
    if (node < n) {
        int j0 = rp[node], j1 = rp[node + 1];
        float acc[8] = {0,0,0,0,0,0,0,0};
        int j = j0;
        for (; j + 4 <= j1; j += 4) {
            int s0 = (int)(unsigned)epack[j + 0];
            int s1 = (int)(unsigned)epack[j + 1];
            int s2 = (int)(unsigned)epack[j + 2];
            int s3 = (int)(unsigned)epack[j + 3];
            uint4 q0 = hw4[(long long)s0 * RS + fq];
            uint4 q1 = hw4[(long long)s1 * RS + fq];
            uint4 q2 = hw4[(long long)s2 * RS + fq];
            uint4 q3 = hw4[(long long)s3 * RS + fq];
            add8(q0, acc); add8(q1, acc); add8(q2, acc); add8(q3, acc);
        }
        for (; j < j1; ++j) {
            uint4 q = hw4[(long long)(unsigned)epack[j] * RS + fq];
            add8(q, acc);
        }
        uint4 qs = hw4[(long long)node * RS + fq];
        add8(qs, acc);                      // + hw'[d] (self term)
        float dv = dis[node];
        #pragma unroll
        for (int i = 0; i < 8; ++i) acc[i] = fmaf(dv, acc[i], b8[i]);
        float4* y4 = (float4*)y;
        long long o = (long long)node * (FOUT / 4) + fq * 2;
        y4[o]     = make_float4(acc[0], acc[1], acc[2], acc[3]);
        y4[o + 1] = make_float4(acc[4], acc[5], acc[6], acc[7]);
        #pragma unroll
        for (int i = 0; i < 8; ++i) {
            lsum[i] += acc[i];
            lsq[i] = fmaf(acc[i], acc[i], lsq[i]);
        }
    }
    #pragma unroll
    for (int i = 0; i < 8; ++i) {
        atomicAdd(&ssum[fq * 8 + i], lsum[i]);
        atomicAdd(&ssq[fq * 8 + i], lsq[i]);
    }
    __syncthreads();
    for (int i = threadIdx.x; i < FOUT; i += 256) {
        atomicAdd(&stats[i], ssum[i]);
        atomicAdd(&stats[64 + i], ssq[i]);
    }
}

// -------- pooling (fused BN-apply+LeakyReLU on layer-3 y): one block per graph ------
__global__ void k_pool_graph(const float* __restrict__ yraw, const int* __restrict__ batch,
                             const float* __restrict__ stats, const float* __restrict__ gma,
                             const float* __restrict__ bta, int n,
                             float* __restrict__ psum, float* __restrict__ pmax,
                             float* __restrict__ pcnt) {
    const int g = blockIdx.x;
    const int f = threadIdx.x & 15;
    float inv_n = 1.0f / (float)n;
    float m = stats[f] * inv_n;
    float var = fmaxf(stats[64 + f] * inv_n - m * m, 0.f);
    float sc = rsqrtf(var + 1e-5f) * gma[f];
    float sh = bta[f] - m * sc;

    __shared__ int s_lo, s_hi;
    if (threadIdx.x == 0) {
        int lo = 0, hi = n;
        while (lo < hi) { int mid = (lo + hi) >> 1; if (batch[mid] < g) lo = mid + 1; else hi = mid; }
        s_lo = lo;
        hi = n;
        while (lo < hi) { int mid = (lo + hi) >> 1; if (batch[mid] < g + 1) lo = mid + 1; else hi = mid; }
        s_hi = lo;
    }
    __syncthreads();
    const int start = s_lo, end = s_hi;
    float lsum = 0.f, lmax = -3.0e38f;
    for (long long idx = (long long)start * 16 + threadIdx.x; idx < (long long)end * 16; idx += blockDim.x) {
        float t = fmaf(yraw[idx], sc, sh);
        float v = t > 0.f ? t : 0.1f * t;
        lsum += v;
        lmax = fmaxf(lmax, v);
    }
    __shared__ float ss[256], sm[256];
    ss[threadIdx.x] = lsum; sm[threadIdx.x] = lmax;
    __syncthreads();
    for (int off = 128; off >= 16; off >>= 1) {
        if (threadIdx.x < off) {
            ss[threadIdx.x] += ss[threadIdx.x + off];
            sm[threadIdx.x] = fmaxf(sm[threadIdx.x], sm[threadIdx.x + off]);
        }
        __syncthreads();
    }
    if (threadIdx.x < 16) {
        psum[g * 16 + threadIdx.x] = ss[threadIdx.x];
        pmax[g * 16 + threadIdx.x] = sm[threadIdx.x];
    }
    if (threadIdx.x == 0) pcnt[g] = (float)(end - start);
}

// ---------------- head ----------------
__global__ void k_head(const float* __restrict__ psum, const float* __restrict__ pmax,
                       const float* __restrict__ pcnt,
                       const float* __restrict__ attn_w, const float* __restrict__ attn_b,
                       const float* __restrict__ fc1_w, const float* __restrict__ fc1_b,
                       const float* __restrict__ fc2_w, const float* __restrict__ fc2_b,
                       const float* __restrict__ out_w, const float* __restrict__ out_b,
                       float* __restrict__ out) {
    int g = threadIdx.x;
    if (g >= GG) return;
    float xs[16], xm[16], xx[16];
    float c = fmaxf(pcnt[g], 1.0f);
    for (int f = 0; f < 16; ++f) {
        xs[f] = psum[(g << 4) + f];
        xm[f] = xs[f] / c;
        xx[f] = pmax[(g << 4) + f];
    }
    float lg[3];
    for (int cI = 0; cI < 3; ++cI) {
        float a = attn_b[cI];
        for (int f = 0; f < 16; ++f) {
            a += xm[f] * attn_w[f * 3 + cI];
            a += xx[f] * attn_w[(16 + f) * 3 + cI];
            a += xs[f] * attn_w[(32 + f) * 3 + cI];
        }
        lg[cI] = a;
    }
    float mx = fmaxf(lg[0], fmaxf(lg[1], lg[2]));
    float e0 = expf(lg[0] - mx), e1 = expf(lg[1] - mx), e2 = expf(lg[2] - mx);
    float inv = 1.0f / (e0 + e1 + e2);
    float a0 = e0 * inv, a1 = e1 * inv, a2 = e2 * inv;
    float xg[16];
    for (int f = 0; f < 16; ++f) xg[f] = a0 * xm[f] + a1 * xx[f] + a2 * xs[f];
    float t1[16];
    for (int j = 0; j < 16; ++j) {
        float a = fc1_b[j];
        for (int k = 0; k < 16; ++k) a += xg[k] * fc1_w[k * 16 + j];
        t1[j] = a > 0.f ? a : 0.1f * a;
    }
    float t2[8];
    for (int j = 0; j < 8; ++j) {
        float a = fc2_b[j];
        for (int k = 0; k < 16; ++k) a += t1[k] * fc2_w[k * 8 + j];
        t2[j] = a > 0.f ? a : 0.1f * a;
    }
    float o = out_b[0];
    for (int k = 0; k < 8; ++k) o += t2[k] * out_w[k];
    o = 1.0f / (1.0f + expf(-o));
    out[g] = o;
}

extern "C" void kernel_launch(void* const* d_in, const int* in_sizes, int n_in,
                              void* d_out, int out_size, void* d_ws, size_t ws_size,
                              hipStream_t stream) {
    const float* x      = (const float*)d_in[0];
    const float* W1     = (const float*)d_in[1];  const float* b1   = (const float*)d_in[2];
    const float* W2     = (const float*)d_in[3];  const float* b2   = (const float*)d_in[4];
    const float* W3     = (const float*)d_in[5];  const float* b3   = (const float*)d_in[6];
    const float* g1     = (const float*)d_in[7];  const float* be1  = (const float*)d_in[8];
    const float* g2     = (const float*)d_in[9];  const float* be2  = (const float*)d_in[10];
    const float* g3     = (const float*)d_in[11]; const float* be3  = (const float*)d_in[12];
    const float* attn_w = (const float*)d_in[13]; const float* attn_b = (const float*)d_in[14];
    const float* fc1_w  = (const float*)d_in[15]; const float* fc1_b  = (const float*)d_in[16];
    const float* fc2_w  = (const float*)d_in[17]; const float* fc2_b  = (const float*)d_in[18];
    const float* out_w  = (const float*)d_in[19]; const float* out_b  = (const float*)d_in[20];
    const int* edge_index = (const int*)d_in[21];
    const int* batch      = (const int*)d_in[22];

    const int N = in_sizes[0] / 128;
    const int E = in_sizes[21] / 2;
    const int* srcp = edge_index;
    const int* dstp = edge_index + E;
    const int nb = (N + 255) / 256;

    char* ws = (char*)d_ws;
    float* dis    = (float*)(ws);                 // N f32
    int*   cnt    = (int*)(ws + 0x80000);         // N int (reused as cursor)
    int*   rp     = (int*)(ws + 0x100000);        // N+1 int
    int*   bsum   = (int*)(ws + 0x180000);        // <=512 int
    float* stats1 = (float*)(ws + 0x182000);      // 128 f32 per layer, 3 layers
    float* stats2 = stats1 + 128;
    float* stats3 = stats2 + 128;
    float* psum   = stats3 + 128;
    float* pmax   = psum + GG * 16;
    float* pcnt   = pmax + GG * 16;
    ull*   epack  = (ull*)(ws + 0x190000);        // E * 8B
    float* buf1   = (float*)(ws + 0x190000 + (size_t)E * 8);  // N*64 f32 (y)
    u16*   hwb    = (u16*)(buf1 + (size_t)N * 64);            // N*64 bf16 (hw')

    // ---- CSR build ----
    hipMemsetAsync(cnt, 0, (size_t)N * 4, stream);
    k_hist<<<(E + 255) / 256, 256, 0, stream>>>(dstp, cnt, E);
    k_dis<<<nb, 256, 0, stream>>>(cnt, dis, N);
    k_scanA<<<nb, 256, 0, stream>>>(cnt, rp, bsum, N);
    k_scanB<<<1, 512, 0, stream>>>(bsum, nb);
    k_scanC<<<nb, 256, 0, stream>>>(rp, bsum, cnt, N, E);
    k_scatter<<<2048, 256, 0, stream>>>(srcp, dstp, cnt, epack, E, N);
    hipMemsetAsync(stats1, 0, 3 * 512, stream);

    // exact-cover agg grids
    const int gr1 = (N + 31) / 32;    // FOUT=64: NPB=32
    const int gr2 = (N + 63) / 64;    // FOUT=32: NPB=64
    const int gr3 = (N + 127) / 128;  // FOUT=16: NPB=128

    // ---- layer 1 (no BN on input) ----
    k_mm<128, 64, false><<<(N + 63) / 64, 256, 0, stream>>>(
        x, W1, dis, nullptr, nullptr, nullptr, hwb, N);
    k_agg<64><<<gr1, 256, 0, stream>>>(hwb, epack, rp, dis, b1, buf1, stats1, N);

    // ---- layer 2 (BN1+lrelu fused into staging) ----
    k_mm<64, 32, true><<<(N + 127) / 128, 256, 0, stream>>>(
        buf1, W2, dis, stats1, g1, be1, hwb, N);
    k_agg<32><<<gr2, 256, 0, stream>>>(hwb, epack, rp, dis, b2, buf1, stats2, N);

    // ---- layer 3 (BN2+lrelu fused) ----
    k_mm<32, 16, true><<<(N + 255) / 256, 256, 0, stream>>>(
        buf1, W3, dis, stats2, g2, be2, hwb, N);
    k_agg<16><<<gr3, 256, 0, stream>>>(hwb, epack, rp, dis, b3, buf1, stats3, N);

    // ---- pooling (BN3+lrelu fused) + head ----
    k_pool_graph<<<GG, 256, 0, stream>>>(buf1, batch, stats3, g3, be3, N, psum, pmax, pcnt);
    k_head<<<1, 64, 0, stream>>>(psum, pmax, pcnt, attn_w, attn_b,
                                 fc1_w, fc1_b, fc2_w, fc2_b, out_w, out_b,
                                 (float*)d_out);
}

// Round 12
// 588.794 us; speedup vs baseline: 1.1753x; 1.0171x over previous
//
#include <hip/hip_runtime.h>

#define GG 64   // num_graphs (fixed by problem)
typedef unsigned long long ull;
typedef unsigned short u16;

__device__ __forceinline__ u16 f2b(float x) {          // fp32 -> bf16 (RN-even)
    unsigned u = __float_as_uint(x);
    return (u16)((u + 0x7FFFu + ((u >> 16) & 1u)) >> 16);
}

// unpack uint4 (8 bf16) and add into acc[8]
__device__ __forceinline__ void add8(const uint4 q, float* acc) {
    acc[0] += __uint_as_float(q.x << 16);
    acc[1] += __uint_as_float(q.x & 0xFFFF0000u);
    acc[2] += __uint_as_float(q.y << 16);
    acc[3] += __uint_as_float(q.y & 0xFFFF0000u);
    acc[4] += __uint_as_float(q.z << 16);
    acc[5] += __uint_as_float(q.z & 0xFFFF0000u);
    acc[6] += __uint_as_float(q.w << 16);
    acc[7] += __uint_as_float(q.w & 0xFFFF0000u);
}

// ---------------- CSR build ----------------
__global__ void k_hist(const int* __restrict__ dst, int* __restrict__ cnt, int E) {
    int e = blockIdx.x * blockDim.x + threadIdx.x;
    if (e < E) atomicAdd(&cnt[dst[e]], 1);
}

__global__ void k_dis(const int* __restrict__ cnt, float* __restrict__ dis, int n) {
    int i = blockIdx.x * blockDim.x + threadIdx.x;
    if (i < n) dis[i] = rsqrtf((float)cnt[i] + 1.0f);
}

__global__ void k_scanA(const int* __restrict__ cnt, int* __restrict__ rp,
                        int* __restrict__ bsum, int n) {
    __shared__ int s[256];
    int i = blockIdx.x * 256 + threadIdx.x;
    int v = (i < n) ? cnt[i] : 0;
    s[threadIdx.x] = v;
    __syncthreads();
    for (int off = 1; off < 256; off <<= 1) {
        int t = (threadIdx.x >= off) ? s[threadIdx.x - off] : 0;
        __syncthreads();
        s[threadIdx.x] += t;
        __syncthreads();
    }
    if (i < n) rp[i] = s[threadIdx.x] - v;
    if (threadIdx.x == 255) bsum[blockIdx.x] = s[255];
}

__global__ void k_scanB(int* __restrict__ bsum, int nb) {
    __shared__ int s[512];
    int v = (threadIdx.x < nb) ? bsum[threadIdx.x] : 0;
    s[threadIdx.x] = v;
    __syncthreads();
    for (int off = 1; off < 512; off <<= 1) {
        int t = (threadIdx.x >= off) ? s[threadIdx.x - off] : 0;
        __syncthreads();
        s[threadIdx.x] += t;
        __syncthreads();
    }
    if (threadIdx.x < nb) bsum[threadIdx.x] = s[threadIdx.x] - v;
}

__global__ void k_scanC(int* __restrict__ rp, const int* __restrict__ bsum,
                        int* __restrict__ cursor, int n, int E) {
    int i = blockIdx.x * 256 + threadIdx.x;
    if (i < n) {
        int r = rp[i] + bsum[blockIdx.x];
        rp[i] = r;
        cursor[i] = r;
    }
    if (i == 0) rp[n] = E;
}

// XCD-partitioned scatter (R11: confirmed ~35% win via single-XCD line ownership)
__global__ __launch_bounds__(256) void k_scatter(const int* __restrict__ src,
                                                 const int* __restrict__ dst,
                                                 int* __restrict__ cursor,
                                                 ull* __restrict__ epack, int E, int n) {
    const int part = blockIdx.x & 7;
    const int nblk = gridDim.x >> 3;
    const int bser = blockIdx.x >> 3;
    const int lo = (int)(((long long)part * n) >> 3);
    const int hi = (part == 7) ? n : (int)(((long long)(part + 1) * n) >> 3);
    for (int e = bser * 256 + threadIdx.x; e < E; e += nblk * 256) {
        int d = dst[e];
        if (d >= lo && d < hi) {
            int s = src[e];
            int pos = atomicAdd(&cursor[d], 1);
            epack[pos] = (ull)(unsigned)s;
        }
    }
}

// ---- tiled GEMM (+optional fused BN-apply+LeakyReLU on input) + dis-fold output ----
template <int FIN, int FOUT, bool BN>
__global__ __launch_bounds__(256) void k_mm(const float* __restrict__ h,
                                            const float* __restrict__ W,
                                            const float* __restrict__ dis,
                                            const float* __restrict__ stats,
                                            const float* __restrict__ gma,
                                            const float* __restrict__ bta,
                                            u16* __restrict__ hw, int n) {
    constexpr int FX  = FOUT / 4;
    constexpr int TY  = 256 / FX;
    constexpr int NT  = TY * 4;
    constexpr int LDA = FIN + ((FOUT == 64) ? 2 : 1);
    __shared__ float sA[NT * LDA];
    __shared__ float sW[FIN * FOUT];
    __shared__ float sSc[FIN], sSh[FIN];

    if (BN && threadIdx.x < FIN) {
        int f = threadIdx.x;
        float inv_n = 1.0f / (float)n;
        float m = stats[f] * inv_n;
        float var = fmaxf(stats[64 + f] * inv_n - m * m, 0.f);
        float sc = rsqrtf(var + 1e-5f) * gma[f];
        sSc[f] = sc;
        sSh[f] = bta[f] - m * sc;
    }
    for (int i = threadIdx.x; i < FIN * FOUT / 4; i += 256)
        ((float4*)sW)[i] = ((const float4*)W)[i];
    if (BN) __syncthreads();

    const int node0 = blockIdx.x * NT;
    constexpr int LD4 = NT * FIN / 4 / 256;
    #pragma unroll
    for (int i = 0; i < LD4; ++i) {
        int idx4 = i * 256 + threadIdx.x;
        int row = idx4 / (FIN / 4);
        int c4  = idx4 % (FIN / 4);
        int gn  = node0 + row;
        float4 v = make_float4(0.f, 0.f, 0.f, 0.f);
        if (gn < n) v = ((const float4*)(h + (long long)gn * FIN))[c4];
        if (BN) {
            int f = c4 * 4;
            float t;
            t = fmaf(v.x, sSc[f + 0], sSh[f + 0]); v.x = t > 0.f ? t : 0.1f * t;
            t = fmaf(v.y, sSc[f + 1], sSh[f + 1]); v.y = t > 0.f ? t : 0.1f * t;
            t = fmaf(v.z, sSc[f + 2], sSh[f + 2]); v.z = t > 0.f ? t : 0.1f * t;
            t = fmaf(v.w, sSc[f + 3], sSh[f + 3]); v.w = t > 0.f ? t : 0.1f * t;
        }
        float* p = &sA[row * LDA + c4 * 4];
        p[0] = v.x; p[1] = v.y; p[2] = v.z; p[3] = v.w;
    }
    __syncthreads();

    const int tx = threadIdx.x % FX;
    const int ty = threadIdx.x / FX;
    float acc[4][4];
    #pragma unroll
    for (int i = 0; i < 4; ++i)
        #pragma unroll
        for (int j = 0; j < 4; ++j) acc[i][j] = 0.f;

    #pragma unroll 8
    for (int k = 0; k < FIN; ++k) {
        float4 wv = *((const float4*)&sW[k * FOUT + tx * 4]);
        float a0 = sA[(ty * 4 + 0) * LDA + k];
        float a1 = sA[(ty * 4 + 1) * LDA + k];
        float a2 = sA[(ty * 4 + 2) * LDA + k];
        float a3 = sA[(ty * 4 + 3) * LDA + k];
        acc[0][0] = fmaf(a0, wv.x, acc[0][0]); acc[0][1] = fmaf(a0, wv.y, acc[0][1]);
        acc[0][2] = fmaf(a0, wv.z, acc[0][2]); acc[0][3] = fmaf(a0, wv.w, acc[0][3]);
        acc[1][0] = fmaf(a1, wv.x, acc[1][0]); acc[1][1] = fmaf(a1, wv.y, acc[1][1]);
        acc[1][2] = fmaf(a1, wv.z, acc[1][2]); acc[1][3] = fmaf(a1, wv.w, acc[1][3]);
        acc[2][0] = fmaf(a2, wv.x, acc[2][0]); acc[2][1] = fmaf(a2, wv.y, acc[2][1]);
        acc[2][2] = fmaf(a2, wv.z, acc[2][2]); acc[2][3] = fmaf(a2, wv.w, acc[2][3]);
        acc[3][0] = fmaf(a3, wv.x, acc[3][0]); acc[3][1] = fmaf(a3, wv.y, acc[3][1]);
        acc[3][2] = fmaf(a3, wv.z, acc[3][2]); acc[3][3] = fmaf(a3, wv.w, acc[3][3]);
    }

    #pragma unroll
    for (int i = 0; i < 4; ++i) {
        int gn = node0 + ty * 4 + i;
        if (gn < n) {
            float dv = dis[gn];
            ushort4 o;
            o.x = f2b(acc[i][0] * dv); o.y = f2b(acc[i][1] * dv);
            o.z = f2b(acc[i][2] * dv); o.w = f2b(acc[i][3] * dv);
            ((ushort4*)(hw + (long long)gn * FOUT))[tx] = o;
        }
    }
}

// ------- CSR aggregation (8x-unrolled gather for MLP) + self + bias + BN stats ------
template <int FOUT>
__global__ __launch_bounds__(256) void k_agg(const u16* __restrict__ hwb,
                                             const ull* __restrict__ epack,
                                             const int* __restrict__ rp,
                                             const float* __restrict__ dis,
                                             const float* __restrict__ bias,
                                             float* __restrict__ y,
                                             float* __restrict__ stats, int n) {
    constexpr int LPN = FOUT / 8;          // lanes per node (uint4 = 8 bf16)
    constexpr int NPB = 256 / LPN;         // nodes per block
    constexpr int RS  = FOUT / 8;          // row stride in uint4
    __shared__ float ssum[FOUT], ssq[FOUT];
    for (int i = threadIdx.x; i < FOUT; i += 256) { ssum[i] = 0.f; ssq[i] = 0.f; }
    __syncthreads();
    const int local = threadIdx.x / LPN;
    const int fq = threadIdx.x % LPN;
    const uint4* hw4 = (const uint4*)hwb;
    float b8[8];
    #pragma unroll
    for (int i = 0; i < 8; ++i) b8[i] = bias[fq * 8 + i];
    float lsum[8] = {0,0,0,0,0,0,0,0}, lsq[8] = {0,0,0,0,0,0,0,0};

    int node = blockIdx.x * NPB + local;
    if (node < n) {
        int j0 = rp[node], j1 = rp[node + 1];
        float acc[8] = {0,0,0,0,0,0,0,0};
        int j = j0;
        for (; j + 8 <= j1; j += 8) {                 // 8 gathers in flight
            int s0 = (int)(unsigned)epack[j + 0];
            int s1 = (int)(unsigned)epack[j + 1];
            int s2 = (int)(unsigned)epack[j + 2];
            int s3 = (int)(unsigned)epack[j + 3];
            int s4 = (int)(unsigned)epack[j + 4];
            int s5 = (int)(unsigned)epack[j + 5];
            int s6 = (int)(unsigned)epack[j + 6];
            int s7 = (int)(unsigned)epack[j + 7];
            uint4 q0 = hw4[(long long)s0 * RS + fq];
            uint4 q1 = hw4[(long long)s1 * RS + fq];
            uint4 q2 = hw4[(long long)s2 * RS + fq];
            uint4 q3 = hw4[(long long)s3 * RS + fq];
            uint4 q4 = hw4[(long long)s4 * RS + fq];
            uint4 q5 = hw4[(long long)s5 * RS + fq];
            uint4 q6 = hw4[(long long)s6 * RS + fq];
            uint4 q7 = hw4[(long long)s7 * RS + fq];
            add8(q0, acc); add8(q1, acc); add8(q2, acc); add8(q3, acc);
            add8(q4, acc); add8(q5, acc); add8(q6, acc); add8(q7, acc);
        }
        for (; j + 2 <= j1; j += 2) {
            int s0 = (int)(unsigned)epack[j + 0];
            int s1 = (int)(unsigned)epack[j + 1];
            uint4 q0 = hw4[(long long)s0 * RS + fq];
            uint4 q1 = hw4[(long long)s1 * RS + fq];
            add8(q0, acc); add8(q1, acc);
        }
        for (; j < j1; ++j) {
            uint4 q = hw4[(long long)(unsigned)epack[j] * RS + fq];
            add8(q, acc);
        }
        uint4 qs = hw4[(long long)node * RS + fq];
        add8(qs, acc);                      // + hw'[d] (self term)
        float dv = dis[node];
        #pragma unroll
        for (int i = 0; i < 8; ++i) acc[i] = fmaf(dv, acc[i], b8[i]);
        float4* y4 = (float4*)y;
        long long o = (long long)node * (FOUT / 4) + fq * 2;
        y4[o]     = make_float4(acc[0], acc[1], acc[2], acc[3]);
        y4[o + 1] = make_float4(acc[4], acc[5], acc[6], acc[7]);
        #pragma unroll
        for (int i = 0; i < 8; ++i) {
            lsum[i] += acc[i];
            lsq[i] = fmaf(acc[i], acc[i], lsq[i]);
        }
    }
    #pragma unroll
    for (int i = 0; i < 8; ++i) {
        atomicAdd(&ssum[fq * 8 + i], lsum[i]);
        atomicAdd(&ssq[fq * 8 + i], lsq[i]);
    }
    __syncthreads();
    for (int i = threadIdx.x; i < FOUT; i += 256) {
        atomicAdd(&stats[i], ssum[i]);
        atomicAdd(&stats[64 + i], ssq[i]);
    }
}

// -------- pooling (fused BN-apply+LeakyReLU on layer-3 y): one block per graph ------
__global__ void k_pool_graph(const float* __restrict__ yraw, const int* __restrict__ batch,
                             const float* __restrict__ stats, const float* __restrict__ gma,
                             const float* __restrict__ bta, int n,
                             float* __restrict__ psum, float* __restrict__ pmax,
                             float* __restrict__ pcnt) {
    const int g = blockIdx.x;
    const int f = threadIdx.x & 15;
    float inv_n = 1.0f / (float)n;
    float m = stats[f] * inv_n;
    float var = fmaxf(stats[64 + f] * inv_n - m * m, 0.f);
    float sc = rsqrtf(var + 1e-5f) * gma[f];
    float sh = bta[f] - m * sc;

    __shared__ int s_lo, s_hi;
    if (threadIdx.x == 0) {
        int lo = 0, hi = n;
        while (lo < hi) { int mid = (lo + hi) >> 1; if (batch[mid] < g) lo = mid + 1; else hi = mid; }
        s_lo = lo;
        hi = n;
        while (lo < hi) { int mid = (lo + hi) >> 1; if (batch[mid] < g + 1) lo = mid + 1; else hi = mid; }
        s_hi = lo;
    }
    __syncthreads();
    const int start = s_lo, end = s_hi;
    float lsum = 0.f, lmax = -3.0e38f;
    for (long long idx = (long long)start * 16 + threadIdx.x; idx < (long long)end * 16; idx += blockDim.x) {
        float t = fmaf(yraw[idx], sc, sh);
        float v = t > 0.f ? t : 0.1f * t;
        lsum += v;
        lmax = fmaxf(lmax, v);
    }
    __shared__ float ss[256], sm[256];
    ss[threadIdx.x] = lsum; sm[threadIdx.x] = lmax;
    __syncthreads();
    for (int off = 128; off >= 16; off >>= 1) {
        if (threadIdx.x < off) {
            ss[threadIdx.x] += ss[threadIdx.x + off];
            sm[threadIdx.x] = fmaxf(sm[threadIdx.x], sm[threadIdx.x + off]);
        }
        __syncthreads();
    }
    if (threadIdx.x < 16) {
        psum[g * 16 + threadIdx.x] = ss[threadIdx.x];
        pmax[g * 16 + threadIdx.x] = sm[threadIdx.x];
    }
    if (threadIdx.x == 0) pcnt[g] = (float)(end - start);
}

// ---------------- head ----------------
__global__ void k_head(const float* __restrict__ psum, const float* __restrict__ pmax,
                       const float* __restrict__ pcnt,
                       const float* __restrict__ attn_w, const float* __restrict__ attn_b,
                       const float* __restrict__ fc1_w, const float* __restrict__ fc1_b,
                       const float* __restrict__ fc2_w, const float* __restrict__ fc2_b,
                       const float* __restrict__ out_w, const float* __restrict__ out_b,
                       float* __restrict__ out) {
    int g = threadIdx.x;
    if (g >= GG) return;
    float xs[16], xm[16], xx[16];
    float c = fmaxf(pcnt[g], 1.0f);
    for (int f = 0; f < 16; ++f) {
        xs[f] = psum[(g << 4) + f];
        xm[f] = xs[f] / c;
        xx[f] = pmax[(g << 4) + f];
    }
    float lg[3];
    for (int cI = 0; cI < 3; ++cI) {
        float a = attn_b[cI];
        for (int f = 0; f < 16; ++f) {
            a += xm[f] * attn_w[f * 3 + cI];
            a += xx[f] * attn_w[(16 + f) * 3 + cI];
            a += xs[f] * attn_w[(32 + f) * 3 + cI];
        }
        lg[cI] = a;
    }
    float mx = fmaxf(lg[0], fmaxf(lg[1], lg[2]));
    float e0 = expf(lg[0] - mx), e1 = expf(lg[1] - mx), e2 = expf(lg[2] - mx);
    float inv = 1.0f / (e0 + e1 + e2);
    float a0 = e0 * inv, a1 = e1 * inv, a2 = e2 * inv;
    float xg[16];
    for (int f = 0; f < 16; ++f) xg[f] = a0 * xm[f] + a1 * xx[f] + a2 * xs[f];
    float t1[16];
    for (int j = 0; j < 16; ++j) {
        float a = fc1_b[j];
        for (int k = 0; k < 16; ++k) a += xg[k] * fc1_w[k * 16 + j];
        t1[j] = a > 0.f ? a : 0.1f * a;
    }
    float t2[8];
    for (int j = 0; j < 8; ++j) {
        float a = fc2_b[j];
        for (int k = 0; k < 16; ++k) a += t1[k] * fc2_w[k * 8 + j];
        t2[j] = a > 0.f ? a : 0.1f * a;
    }
    float o = out_b[0];
    for (int k = 0; k < 8; ++k) o += t2[k] * out_w[k];
    o = 1.0f / (1.0f + expf(-o));
    out[g] = o;
}

extern "C" void kernel_launch(void* const* d_in, const int* in_sizes, int n_in,
                              void* d_out, int out_size, void* d_ws, size_t ws_size,
                              hipStream_t stream) {
    const float* x      = (const float*)d_in[0];
    const float* W1     = (const float*)d_in[1];  const float* b1   = (const float*)d_in[2];
    const float* W2     = (const float*)d_in[3];  const float* b2   = (const float*)d_in[4];
    const float* W3     = (const float*)d_in[5];  const float* b3   = (const float*)d_in[6];
    const float* g1     = (const float*)d_in[7];  const float* be1  = (const float*)d_in[8];
    const float* g2     = (const float*)d_in[9];  const float* be2  = (const float*)d_in[10];
    const float* g3     = (const float*)d_in[11]; const float* be3  = (const float*)d_in[12];
    const float* attn_w = (const float*)d_in[13]; const float* attn_b = (const float*)d_in[14];
    const float* fc1_w  = (const float*)d_in[15]; const float* fc1_b  = (const float*)d_in[16];
    const float* fc2_w  = (const float*)d_in[17]; const float* fc2_b  = (const float*)d_in[18];
    const float* out_w  = (const float*)d_in[19]; const float* out_b  = (const float*)d_in[20];
    const int* edge_index = (const int*)d_in[21];
    const int* batch      = (const int*)d_in[22];

    const int N = in_sizes[0] / 128;
    const int E = in_sizes[21] / 2;
    const int* srcp = edge_index;
    const int* dstp = edge_index + E;
    const int nb = (N + 255) / 256;

    char* ws = (char*)d_ws;
    float* dis    = (float*)(ws);                 // N f32
    int*   cnt    = (int*)(ws + 0x80000);         // N int (reused as cursor)
    int*   rp     = (int*)(ws + 0x100000);        // N+1 int
    int*   bsum   = (int*)(ws + 0x180000);        // <=512 int
    float* stats1 = (float*)(ws + 0x182000);      // 128 f32 per layer, 3 layers
    float* stats2 = stats1 + 128;
    float* stats3 = stats2 + 128;
    float* psum   = stats3 + 128;
    float* pmax   = psum + GG * 16;
    float* pcnt   = pmax + GG * 16;
    ull*   epack  = (ull*)(ws + 0x190000);        // E * 8B
    float* buf1   = (float*)(ws + 0x190000 + (size_t)E * 8);  // N*64 f32 (y)
    u16*   hwb    = (u16*)(buf1 + (size_t)N * 64);            // N*64 bf16 (hw')

    // ---- CSR build ----
    hipMemsetAsync(cnt, 0, (size_t)N * 4, stream);
    k_hist<<<(E + 255) / 256, 256, 0, stream>>>(dstp, cnt, E);
    k_dis<<<nb, 256, 0, stream>>>(cnt, dis, N);
    k_scanA<<<nb, 256, 0, stream>>>(cnt, rp, bsum, N);
    k_scanB<<<1, 512, 0, stream>>>(bsum, nb);
    k_scanC<<<nb, 256, 0, stream>>>(rp, bsum, cnt, N, E);
    k_scatter<<<2048, 256, 0, stream>>>(srcp, dstp, cnt, epack, E, N);
    hipMemsetAsync(stats1, 0, 3 * 512, stream);

    // exact-cover agg grids
    const int gr1 = (N + 31) / 32;    // FOUT=64: NPB=32
    const int gr2 = (N + 63) / 64;    // FOUT=32: NPB=64
    const int gr3 = (N + 127) / 128;  // FOUT=16: NPB=128

    // ---- layer 1 (no BN on input) ----
    k_mm<128, 64, false><<<(N + 63) / 64, 256, 0, stream>>>(
        x, W1, dis, nullptr, nullptr, nullptr, hwb, N);
    k_agg<64><<<gr1, 256, 0, stream>>>(hwb, epack, rp, dis, b1, buf1, stats1, N);

    // ---- layer 2 (BN1+lrelu fused into staging) ----
    k_mm<64, 32, true><<<(N + 127) / 128, 256, 0, stream>>>(
        buf1, W2, dis, stats1, g1, be1, hwb, N);
    k_agg<32><<<gr2, 256, 0, stream>>>(hwb, epack, rp, dis, b2, buf1, stats2, N);

    // ---- layer 3 (BN2+lrelu fused) ----
    k_mm<32, 16, true><<<(N + 255) / 256, 256, 0, stream>>>(
        buf1, W3, dis, stats2, g2, be2, hwb, N);
    k_agg<16><<<gr3, 256, 0, stream>>>(hwb, epack, rp, dis, b3, buf1, stats3, N);

    // ---- pooling (BN3+lrelu fused) + head ----
    k_pool_graph<<<GG, 256, 0, stream>>>(buf1, batch, stats3, g3, be3, N, psum, pmax, pcnt);
    k_head<<<1, 64, 0, stream>>>(psum, pmax, pcnt, attn_w, attn_b,
                                 fc1_w, fc1_b, fc2_w, fc2_b, out_w, out_b,
                                 (float*)d_out);
}